// Round 1
// baseline (257.885 us; speedup 1.0000x reference)
//
#include <hip/hip_runtime.h>

#define KCODES 4096
#define NROWS  32768
#define DIM    256           // K (plain bf16)
#define BM     128
#define BN     64
#define BK     64
#define NKT    (DIM / BK)    // 4 k-chunks
#define NJG    4             // j-groups (grid dim)
#define NJB    (KCODES / (BN * NJG))   // 16 j-tiles per block

typedef __attribute__((ext_vector_type(8))) short  short8;
typedef __attribute__((ext_vector_type(4))) float  float4v;

__device__ inline unsigned short f2bf(float f) {
    unsigned u = __float_as_uint(f);
    unsigned r = (u >> 16) & 1u;
    return (unsigned short)((u + 0x7FFFu + r) >> 16);   // RNE
}
__device__ inline void load_lds16(const void* g, void* l) {
    __builtin_amdgcn_global_load_lds((const __attribute__((address_space(1))) void*)g,
                                     (__attribute__((address_space(3))) void*)l, 16, 0, 0);
}

// ---------------- kernel 0: codebook squared norms ----------------
__global__ __launch_bounds__(256) void csq_kernel(const float* __restrict__ cb,
                                                  float* __restrict__ csq) {
    int code = blockIdx.x * 256 + threadIdx.x;
    if (code < KCODES) {
        const float4* row = (const float4*)(cb + (size_t)code * DIM);
        float s = 0.f;
        #pragma unroll 8
        for (int i = 0; i < DIM / 4; ++i) {
            float4 v = row[i];
            s += v.x * v.x + v.y * v.y + v.z * v.z + v.w * v.w;
        }
        csq[code] = s;
    }
}

// ---------------- kernel 1: cb -> bf16 plane ----------------
__global__ __launch_bounds__(256) void conv_kernel(const float* __restrict__ cb,
                                                   unsigned short* __restrict__ B2) {
    const int idx = blockIdx.x * 256 + threadIdx.x;
    float4 v = ((const float4*)cb)[idx];
    ushort4 h = { f2bf(v.x), f2bf(v.y), f2bf(v.z), f2bf(v.w) };
    ((ushort4*)B2)[idx] = h;
}

// ---------------- kernel 2: K=256 bf16 GEMM, A resident in LDS ----------------
// BN=64, double-buffered B stage, counted vmcnt (T4), raw barriers, setprio (T5).
// grid = 1024: jg = bid & 3, mB = bid >> 2
__global__ __launch_bounds__(256, 2) void gemm_top2_kernel(const float* __restrict__ x,
                                                           const unsigned short* __restrict__ B2,
                                                           const float* __restrict__ csq,
                                                           float4* __restrict__ pairs) {
    // A: 4 kt-regions x 1024 slots x 8 bf16; slot(kt, r, kg) = kt*1024 + r*8 + (kg ^ (r&7))
    __shared__ unsigned short sA[4096 * 8];   // 64 KB
    // B double buffer: 2 x (64 rows x 8 kg) slots x 8 bf16 = 2 x 8 KB
    __shared__ unsigned short sB[2][4096];    // 16 KB (aliased by merge arrays at the end)

    const int tid = threadIdx.x;
    const int lane = tid & 63, wid = tid >> 6;
    const int wm = wid >> 1, wn = wid & 1;
    const int c = lane & 15, q = lane >> 4;
    const int jg = blockIdx.x & (NJG - 1);
    const int mB = blockIdx.x >> 2;
    const int mBase = mB * BM;

    // ---- stage A once: fp32 x -> bf16 LDS (XOR-swizzled) ----
    #pragma unroll
    for (int i = 0; i < 16; ++i) {
        int sid = i * 256 + tid;          // slot 0..4095
        int kt  = sid >> 10, rem = sid & 1023;
        int r   = rem >> 3,  kp  = rem & 7;
        int kgl = kp ^ (r & 7);
        const float4* xs = (const float4*)(x + (size_t)(mBase + r) * DIM + kt * BK + kgl * 8);
        float4 v0 = xs[0], v1 = xs[1];
        unsigned short h[8] = { f2bf(v0.x), f2bf(v0.y), f2bf(v0.z), f2bf(v0.w),
                                f2bf(v1.x), f2bf(v1.y), f2bf(v1.z), f2bf(v1.w) };
        *(short8*)&sA[(size_t)sid * 8] = *(short8*)h;
    }

    // B staging descriptors (XOR-swizzled). Per stage: 8 KB = 2 x load_lds16/thread.
    unsigned gBrel[2];
    int ldsOff[2];
    #pragma unroll
    for (int i = 0; i < 2; ++i) {
        int s  = wid * 128 + i * 64 + lane;   // slot 0..511
        int r  = s >> 3, kgp = s & 7;
        int kg = kgp ^ (r & 7);
        gBrel[i]  = (unsigned)r * DIM + kg * 8;
        ldsOff[i] = (wid * 128 + i * 64) * 8;  // wave-uniform ushort offset
    }

#define STAGE(JJ, KT, PAR) do {                                                        \
        const unsigned short* gb = B2 + (size_t)((jg * NJB + (JJ)) * BN) * DIM + (KT) * BK; \
        load_lds16(gb + gBrel[0], &sB[PAR][ldsOff[0]]);                                \
        load_lds16(gb + gBrel[1], &sB[PAR][ldsOff[1]]);                                \
    } while (0)

#define TOP2(D, K, S) do {                                   \
        bool f1 = (D) < rv1[S];                              \
        bool f2 = (D) < rv2[S];                              \
        rv2[S] = f1 ? rv1[S] : (f2 ? (D) : rv2[S]);          \
        ri2[S] = f1 ? ri1[S] : (f2 ? (K) : ri2[S]);          \
        rv1[S] = f1 ? (D) : rv1[S];                          \
        ri1[S] = f1 ? (K) : ri1[S];                          \
    } while (0)

    // running per-lane top-2 for the 16 (mi,r) row-slots, carried across all 16 j-tiles
    float rv1[16], rv2[16]; int ri1[16], ri2[16];
    #pragma unroll
    for (int s = 0; s < 16; ++s) { rv1[s] = INFINITY; rv2[s] = INFINITY; ri1[s] = 0x7FFFFFFF; ri2[s] = 0x7FFFFFFF; }

    // ---- pipeline prologue: drain A-stage loads, prefetch first two B chunks ----
    asm volatile("s_waitcnt vmcnt(0)" ::: "memory");
    STAGE(0, 0, 0);
    STAGE(0, 1, 1);
    asm volatile("s_waitcnt lgkmcnt(0)" ::: "memory");   // A ds_writes done
    __builtin_amdgcn_s_barrier();                        // A visible; B(0),B(1) in flight

    #pragma unroll 1
    for (int jj = 0; jj < NJB; ++jj) {
        float4v acc[4][2];
        #pragma unroll
        for (int mi = 0; mi < 4; ++mi)
            #pragma unroll
            for (int ni = 0; ni < 2; ++ni)
                #pragma unroll
                for (int e = 0; e < 4; ++e) acc[mi][ni][e] = 0.f;

        #pragma unroll
        for (int kt = 0; kt < NKT; ++kt) {
            // counted wait: current chunk landed, next chunk may stay in flight
            if (kt == 3 && jj == NJB - 1)
                asm volatile("s_waitcnt vmcnt(0)" ::: "memory");
            else
                asm volatile("s_waitcnt vmcnt(2)" ::: "memory");
            __builtin_amdgcn_s_barrier();
            asm volatile("" ::: "memory");

            const unsigned short* sBb = sB[kt & 1];
            #pragma unroll
            for (int ks = 0; ks < 2; ++ks) {
                short8 aF[4], bF[2];
                const int kg = ks * 4 + q;
                #pragma unroll
                for (int mi = 0; mi < 4; ++mi) {
                    int r = wm * 64 + mi * 16 + c;
                    aF[mi] = *(const short8*)&sA[(size_t)(kt * 1024 + r * 8 + (kg ^ (r & 7))) * 8];
                }
                #pragma unroll
                for (int ni = 0; ni < 2; ++ni) {
                    int r = wn * 32 + ni * 16 + c;
                    bF[ni] = *(const short8*)&sBb[(size_t)(r * 8 + (kg ^ (r & 7))) * 8];
                }
                __builtin_amdgcn_s_setprio(1);
                #pragma unroll
                for (int mi = 0; mi < 4; ++mi)
                    #pragma unroll
                    for (int ni = 0; ni < 2; ++ni)
                        acc[mi][ni] = __builtin_amdgcn_mfma_f32_16x16x32_bf16(aF[mi], bF[ni], acc[mi][ni], 0, 0, 0);
                __builtin_amdgcn_s_setprio(0);
            }

            asm volatile("" ::: "memory");
            __builtin_amdgcn_s_barrier();       // all waves done reading sB[kt&1]
            asm volatile("" ::: "memory");

            if (kt == 0)      STAGE(jj, 2, 0);
            else if (kt == 1) STAGE(jj, 3, 1);
            else if (kt == 2) { if (jj + 1 < NJB) STAGE(jj + 1, 0, 0); }
            // kt == 3: next-tile stage issued below, after the csq loads
        }

        // ---- per-j epilogue: dist = csq - 2*dot ; update running top-2 (ascending k) ----
        const int jBase = (jg * NJB + jj) * BN;
        float cs0 = csq[jBase + wn * 32 + c];          // issued BEFORE the last stage so the
        float cs1 = csq[jBase + wn * 32 + 16 + c];     // compiler's wait is vmcnt(2), not 0
        asm volatile("" ::: "memory");
        if (jj + 1 < NJB) STAGE(jj + 1, 1, 1);         // overlaps with epilogue VALU below

        #pragma unroll
        for (int mi = 0; mi < 4; ++mi)
            #pragma unroll
            for (int r = 0; r < 4; ++r) {
                const int sI = mi * 4 + r;
                float d0 = fmaf(-2.f, acc[mi][0][r], cs0);
                int   k0 = jBase + wn * 32 + c;
                TOP2(d0, k0, sI);
                float d1 = fmaf(-2.f, acc[mi][1][r], cs1);
                int   k1 = jBase + wn * 32 + 16 + c;
                TOP2(d1, k1, sI);
            }
    }

    // ---- merge scratch aliased over sB (no longer needed) ----
    __syncthreads();
    char* mbase = (char*)sB;
    float (*sV1)[BM] = (float(*)[BM])(mbase);
    int   (*sI1)[BM] = (int  (*)[BM])(mbase + 1024);
    float (*sV2)[BM] = (float(*)[BM])(mbase + 2048);
    int   (*sI2)[BM] = (int  (*)[BM])(mbase + 3072);

    // once per block: butterfly lex-merge of top-2 over the 16 c-lanes
    #pragma unroll
    for (int s = 0; s < 16; ++s) {
        float a1 = rv1[s], a2 = rv2[s]; int b1 = ri1[s], b2 = ri2[s];
        #pragma unroll
        for (int m = 1; m < 16; m <<= 1) {
            float w1 = __shfl_xor(a1, m), w2 = __shfl_xor(a2, m);
            int   j1 = __shfl_xor(b1, m), j2 = __shfl_xor(b2, m);
            bool lt = (w1 < a1) || (w1 == a1 && j1 < b1);
            float f1v = lt ? w1 : a1;  int g1 = lt ? j1 : b1;
            float o1 = lt ? a1 : w1;   int p1 = lt ? b1 : j1;
            float o2 = lt ? w2 : a2;   int p2 = lt ? j2 : b2;
            bool lt2 = (o1 < o2) || (o1 == o2 && p1 < p2);
            a1 = f1v; b1 = g1;
            a2 = lt2 ? o1 : o2; b2 = lt2 ? p1 : p2;
        }
        if (c == 0) {
            int row = wm * 64 + (s >> 2) * 16 + q * 4 + (s & 3);
            sV1[wn][row] = a1; sI1[wn][row] = b1;
            sV2[wn][row] = a2; sI2[wn][row] = b2;
        }
    }
    __syncthreads();

    // merge the two code-halves, write (v1,i1,v2,i2) per row for this j-group
    if (tid < BM) {
        float a1 = sV1[0][tid], a2 = sV2[0][tid];
        int   b1 = sI1[0][tid], b2 = sI2[0][tid];
        float w1 = sV1[1][tid], w2 = sV2[1][tid];
        int   j1 = sI1[1][tid], j2 = sI2[1][tid];
        bool lt = (w1 < a1) || (w1 == a1 && j1 < b1);
        float f1 = lt ? w1 : a1;  int g1 = lt ? j1 : b1;
        float o1 = lt ? a1 : w1;  int p1 = lt ? b1 : j1;
        float o2 = lt ? w2 : a2;  int p2 = lt ? j2 : b2;
        bool lt2 = (o1 < o2) || (o1 == o2 && p1 < p2);
        float s2v = lt2 ? o1 : o2; int s2i = lt2 ? p1 : p2;
        float4 outp;
        outp.x = f1;  outp.y = __int_as_float(g1);
        outp.z = s2v; outp.w = __int_as_float(s2i);
        pairs[(size_t)jg * NROWS + mBase + tid] = outp;   // [jg][row], coalesced
    }
#undef STAGE
#undef TOP2
}

// ---------------- kernel 3: merge 4 group-top-2 pairs -> top-4 indices ----------------
__global__ __launch_bounds__(256) void merge_kernel(const float4* __restrict__ pairs,
                                                    int* __restrict__ top4) {
    const int row = blockIdx.x * 256 + threadIdx.x;
    float tv[4] = { INFINITY, INFINITY, INFINITY, INFINITY };
    int   tk[4] = { 0x7FFFFFFF, 0x7FFFFFFF, 0x7FFFFFFF, 0x7FFFFFFF };
    for (int j = 0; j < NJG; ++j) {
        float4 p = pairs[(size_t)j * NROWS + row];
        #pragma unroll
        for (int h = 0; h < 2; ++h) {
            float v = h ? p.z : p.x;
            int   k = __float_as_int(h ? p.w : p.y);
            if (v < tv[3] || (v == tv[3] && k < tk[3])) {
                tv[3] = v; tk[3] = k;
                #pragma unroll
                for (int t = 3; t > 0; --t) {
                    bool lt = (tv[t] < tv[t-1]) || (tv[t] == tv[t-1] && tk[t] < tk[t-1]);
                    if (lt) {
                        float fv = tv[t]; tv[t] = tv[t-1]; tv[t-1] = fv;
                        int   fk = tk[t]; tk[t] = tk[t-1]; tk[t-1] = fk;
                    }
                }
            }
        }
    }
    #pragma unroll
    for (int t = 0; t < 4; ++t) top4[(size_t)row * 4 + t] = tk[t];
}

// ---------------- kernel 4: rescore with exact fp32 recipe + gather + loss ----------------
__global__ __launch_bounds__(256) void rescore_kernel(const float* __restrict__ x,
                                                      const float* __restrict__ cb,
                                                      const float* __restrict__ csq,
                                                      const int* __restrict__ top4,
                                                      float* __restrict__ out,
                                                      float* __restrict__ partial) {
    __shared__ float sx[64 * 256];   // 64 rows of x, raw fp32
    __shared__ float rv[64][4];
    __shared__ int   rk[64][4];
    __shared__ int   pick[64];
    __shared__ float sred[256];

    const int tid = threadIdx.x;
    const int rowBase = blockIdx.x * 64;
    const float4* x4 = (const float4*)x;
    const float4* c4 = (const float4*)cb;

    #pragma unroll
    for (int i = 0; i < 16; ++i) {
        int g = tid + i * 256;
        ((float4*)sx)[g] = x4[(size_t)rowBase * 64 + g];
    }
    __syncthreads();

    // one thread per (row, candidate): serial fmaf chain, ascending d
    {
        const int r = tid >> 2, ci = tid & 3;
        const int k = top4[(size_t)(rowBase + r) * 4 + ci];
        const float4* cr = c4 + (size_t)k * 64;
        const float4* xr = (const float4*)sx + r * 64;
        float acc = 0.f;
        for (int d4 = 0; d4 < 64; ++d4) {
            float4 cv = cr[d4];
            float4 xv = xr[d4];
            acc = fmaf(xv.x, cv.x, acc);
            acc = fmaf(xv.y, cv.y, acc);
            acc = fmaf(xv.z, cv.z, acc);
            acc = fmaf(xv.w, cv.w, acc);
        }
        float cs = csq[k];
        float v = cs - 2.0f * acc;
        rv[r][ci] = v;
        rk[r][ci] = k;
    }
    __syncthreads();

    if (tid < 64) {
        float bv = rv[tid][0];
        int   bi = rk[tid][0];
        #pragma unroll
        for (int t = 1; t < 4; ++t) {
            float v = rv[tid][t];
            int  ii = rk[tid][t];
            if (v < bv || (v == bv && ii < bi)) { bv = v; bi = ii; }
        }
        pick[tid] = bi;
    }
    __syncthreads();

    float s = 0.f;
    #pragma unroll
    for (int i = 0; i < 16; ++i) {
        int g = tid + i * 256;
        int r = g >> 6, col = g & 63;
        int k = pick[r];
        float4 cv = c4[(size_t)k * 64 + col];
        float4 xv = ((const float4*)sx)[g];
        ((float4*)out)[(size_t)rowBase * 64 + g] = cv;
        float dx = cv.x - xv.x, dy = cv.y - xv.y, dz = cv.z - xv.z, dw = cv.w - xv.w;
        s += dx * dx + dy * dy + dz * dz + dw * dw;
    }
    sred[tid] = s;
    __syncthreads();
    for (int off = 128; off > 0; off >>= 1) {
        if (tid < off) sred[tid] += sred[tid + off];
        __syncthreads();
    }
    if (tid == 0) partial[blockIdx.x] = sred[0];
}

// ---------------- kernel 5: finalize loss ----------------
__global__ __launch_bounds__(256) void finalize_kernel(const float* __restrict__ partial,
                                                       float* __restrict__ loss_out) {
    __shared__ float sred[256];
    const int tid = threadIdx.x;
    float s = 0.f;
    for (int i = tid; i < 512; i += 256) s += partial[i];
    sred[tid] = s;
    __syncthreads();
    for (int off = 128; off > 0; off >>= 1) {
        if (tid < off) sred[tid] += sred[tid + off];
        __syncthreads();
    }
    if (tid == 0) loss_out[0] = sred[0] * 1.25f / 8388608.0f;
}

extern "C" void kernel_launch(void* const* d_in, const int* in_sizes, int n_in,
                              void* d_out, int out_size, void* d_ws, size_t ws_size,
                              hipStream_t stream) {
    const float* x  = (const float*)d_in[0];
    const float* cb = (const float*)d_in[1];
    float* out = (float*)d_out;

    char* ws = (char*)d_ws;
    unsigned short* B2 = (unsigned short*)ws;                          // 2 MB
    float* csq         = (float*)(ws + 2097152);                       // 16 KB
    int*   top4        = (int*)(ws + 2097152 + 16384);                 // 512 KB
    float* partial     = (float*)(ws + 2097152 + 16384 + 524288);      // 2 KB

    // pairs scratch lives in d_out (2 MB used), fully overwritten by rescore afterwards
    float4* pairs = (float4*)d_out;

    conv_kernel<<<KCODES * 64 / 256, 256, 0, stream>>>(cb, B2);
    csq_kernel<<<KCODES / 256, 256, 0, stream>>>(cb, csq);
    gemm_top2_kernel<<<(NROWS / BM) * NJG, 256, 0, stream>>>(x, B2, csq, pairs);
    merge_kernel<<<NROWS / 256, 256, 0, stream>>>(pairs, top4);
    rescore_kernel<<<NROWS / 64, 256, 0, stream>>>(x, cb, csq, top4, out, partial);
    finalize_kernel<<<1, 256, 0, stream>>>(partial, out + 8388608);
}